// Round 13
// baseline (223.382 us; speedup 1.0000x reference)
//
#include <hip/hip_runtime.h>
#include <cstdint>
#include <cstddef>

typedef unsigned short u16;
typedef __attribute__((ext_vector_type(8))) short s16x8;   // 8 bf16 (4 VGPRs) MFMA frag
typedef __attribute__((ext_vector_type(4))) float f32x4;   // MFMA accum frag

#define DEV static __device__ __forceinline__

constexpr int C = 384;
constexpr int HEADS = 12;
constexpr int NQKV = 3 * C;            // 1152
constexpr int TOK = 16 * 64 * 64;      // 65536 tokens

// workspace layout (bytes)
constexpr size_t OFF_QKVW = 0;                                        // 1152x384 bf16
constexpr size_t OFF_PROJW = OFF_QKVW + (size_t)NQKV * C * 2;         // 384x384 bf16
constexpr size_t OFF_BIAS  = OFF_PROJW + (size_t)C * C * 2;           // 12x64x64 f32 (TRANSPOSED: [h][j][i])
constexpr size_t OFF_XG    = OFF_BIAS + (size_t)HEADS * 64 * 64 * 4;  // 65536x384 bf16
constexpr size_t OFF_QN    = OFF_XG + (size_t)TOK * C * 2;            // [1024][12][64][32] bf16 (raw q)
constexpr size_t OFF_KN    = OFF_QN + (size_t)TOK * C * 2;            // raw k
constexpr size_t OFF_VT    = OFF_KN + (size_t)TOK * C * 2;            // [1024][12][32][64] bf16
constexpr size_t OFF_MLP   = OFF_VT + (size_t)TOK * C * 2;            // 225x12 f32
constexpr size_t OFF_AO    = OFF_XG;   // ao [12][65536][32] bf16 aliases xg (dead after qkv)

DEV u16 f2bf(float f) {
  union { float f; uint32_t u; } v; v.f = f;
  uint32_t r = v.u + 0x7FFFu + ((v.u >> 16) & 1u);   // round-to-nearest-even
  return (u16)(r >> 16);
}

DEV float bf2f(short h) {
  union { uint32_t u; float f; } v; v.u = ((uint32_t)(u16)h) << 16;
  return v.f;
}

DEV void async16(const u16* g, u16* l) {
  __builtin_amdgcn_global_load_lds((const __attribute__((address_space(1))) uint32_t*)g,
                                   (__attribute__((address_space(3))) uint32_t*)l, 16, 0, 0);
}

// ---------------- prep: bf16 weight conversion + shifted window gather of x ----------------
__global__ __launch_bounds__(256) void prep_kernel(
    const float* __restrict__ x, const float* __restrict__ qkv_w,
    const float* __restrict__ proj_w, u16* __restrict__ wq,
    u16* __restrict__ wp, u16* __restrict__ xg) {
  int idx = blockIdx.x * 256 + threadIdx.x;
  constexpr int QW = NQKV * C / 8;      // 55296 chunks of 8
  constexpr int PW = C * C / 8;         // 18432
  const float* src;
  u16* dst;
  if (idx < QW) {
    src = qkv_w + (size_t)idx * 8; dst = wq + (size_t)idx * 8;
  } else if (idx < QW + PW) {
    int i = idx - QW;
    src = proj_w + (size_t)i * 8; dst = wp + (size_t)i * 8;
  } else {
    int i = idx - QW - PW;              // 0 .. 3145727
    int r = i / 48, c8 = i % 48;        // token row, 8-elem chunk
    int b = r >> 12, w = (r >> 6) & 63, t = r & 63;
    int y  = ((w >> 3) * 8 + (t >> 3) + 4) & 63;   // roll(-4): xr[y] = x[(y+4)%64]
    int xc = ((w & 7) * 8 + (t & 7) + 4) & 63;
    src = x + (((size_t)(b * 64 + y)) * 64 + xc) * C + c8 * 8;
    dst = xg + (size_t)r * C + (size_t)c8 * 8;
  }
  float4 a = ((const float4*)src)[0];
  float4 bq = ((const float4*)src)[1];
  union { u16 h[8]; uint4 v; } o;
  o.h[0] = f2bf(a.x);  o.h[1] = f2bf(a.y);  o.h[2] = f2bf(a.z);  o.h[3] = f2bf(a.w);
  o.h[4] = f2bf(bq.x); o.h[5] = f2bf(bq.y); o.h[6] = f2bf(bq.z); o.h[7] = f2bf(bq.w);
  *(uint4*)dst = o.v;
}

// ---------------- cpb MLP (parallel over 225 points x 12 heads) ----------------
__global__ __launch_bounds__(256) void bias_mlp_kernel(
    const float* __restrict__ w1, const float* __restrict__ b1,
    const float* __restrict__ w2, float* __restrict__ mlp_out) {
  const int gid = blockIdx.x * 256 + threadIdx.x;
  if (gid >= 225 * 12) return;
  const int pt = gid / 12, q = gid % 12;
  const int a = pt / 15, b = pt % 15;
  const float dy = (float)(a - 7) * (8.f / 7.f);
  const float dx = (float)(b - 7) * (8.f / 7.f);
  const float t0 = copysignf(log2f(fabsf(dy) + 1.f) * (1.f / 3.f), dy);
  const float t1 = copysignf(log2f(fabsf(dx) + 1.f) * (1.f / 3.f), dx);
  float acc = 0.f;
  for (int j = 0; j < 512; ++j) {
    const float hh = fmaxf(w1[2 * j] * t0 + w1[2 * j + 1] * t1 + b1[j], 0.f);
    acc += hh * w2[q * 512 + j];
  }
  mlp_out[gid] = acc;
}

// ---------------- expand to 16*sigmoid bias, TRANSPOSED (12,[j=64],[i=64]) f32 ----------------
__global__ __launch_bounds__(256) void bias_expand_kernel(
    const float* __restrict__ mlp_out, float* __restrict__ biasf) {
  const int o = blockIdx.x * 256 + threadIdx.x;   // < 49152, enumerates (h, j, i)
  const int i = o & 63, j = (o >> 6) & 63, h = o >> 12;
  const int e = ((i >> 3) - (j >> 3) + 7) * 15 + ((i & 7) - (j & 7) + 7);
  const float v = mlp_out[e * 12 + h];
  biasf[o] = 16.f / (1.f + __expf(-v));       // biasT[h][j][i] = bias(i,j)
}

// ---------------- QKV GEMM (128x128, BK=64, dbuf, 8 waves) + epilogue ----------------
// LDS tile per matrix per buf: 128 rows x 64 k, row r = 128B at byte r*128;
// granule g (16B) at ((g ^ (r&7))*16). Staged linearly by chunk c with the
// inverse swizzle applied on the SOURCE k-granule (rule #21).
__global__ __launch_bounds__(512, 2) void qkv_kernel(
    const u16* __restrict__ xg, const u16* __restrict__ wq,
    const float* __restrict__ qkv_b,
    u16* __restrict__ qn, u16* __restrict__ kn, u16* __restrict__ vt) {
  __shared__ __attribute__((aligned(16))) u16 smem[4][128 * 64];   // A0 A1 B0 B1 = 64KB
  const int tid = threadIdx.x, lane = tid & 63, wid = tid >> 6;
  const int l15 = lane & 15, qrt = lane >> 4;
  const int bid = blockIdx.x;
  const int swz = (bid & 7) * 576 + (bid >> 3);
  const int n_blk = swz % 9, m_blk = swz / 9;
  const int m0 = m_blk * 128, n0 = n_blk * 128;
  const int wm = wid & 3, wn = wid >> 2;       // wave tile: 32 rows x 64 cols

  auto stage = [&](int buf, int t) {
    const int k0 = t * 64;
    #pragma unroll
    for (int it = 0; it < 2; ++it) {
      const int c = it * 512 + tid;           // 16B chunk 0..1023
      const int r = c >> 3;
      const int g = (c & 7) ^ (r & 7);
      async16(xg + (size_t)(m0 + r) * C + k0 + g * 8, &smem[buf][c * 8]);
      async16(wq + (size_t)(n0 + r) * C + k0 + g * 8, &smem[2 + buf][c * 8]);
    }
  };
  auto ldfrag = [&](const u16* base, int row, int g) -> s16x8 {
    return *(const s16x8*)((const char*)base + row * 128 + ((g ^ (row & 7)) * 16));
  };

  f32x4 acc[2][4];
  #pragma unroll
  for (int i = 0; i < 2; ++i)
    #pragma unroll
    for (int j = 0; j < 4; ++j) acc[i][j] = f32x4{0.f, 0.f, 0.f, 0.f};

  stage(0, 0);
  for (int t = 0; t < 6; ++t) {
    const int buf = t & 1;
    asm volatile("s_waitcnt vmcnt(0)" ::: "memory");
    __syncthreads();
    if (t < 5) stage(buf ^ 1, t + 1);
    s16x8 af[2][2], bf[2][4];
    #pragma unroll
    for (int kk = 0; kk < 2; ++kk) {
      const int g = kk * 4 + qrt;
      #pragma unroll
      for (int mi = 0; mi < 2; ++mi)
        af[kk][mi] = ldfrag(smem[buf], wm * 32 + mi * 16 + l15, g);
      #pragma unroll
      for (int ni = 0; ni < 4; ++ni)
        bf[kk][ni] = ldfrag(smem[2 + buf], wn * 64 + ni * 16 + l15, g);
    }
    #pragma unroll
    for (int kk = 0; kk < 2; ++kk)
      #pragma unroll
      for (int mi = 0; mi < 2; ++mi)
        #pragma unroll
        for (int ni = 0; ni < 4; ++ni)
          acc[mi][ni] = __builtin_amdgcn_mfma_f32_16x16x32_bf16(af[kk][mi], bf[kk][ni], acc[mi][ni], 0, 0, 0);
  }

  const int sec = n0 / C;                 // 0=q 1=k 2=v
  const int colbase = n0 + wn * 64;
  float qb[4];
  #pragma unroll
  for (int ni = 0; ni < 4; ++ni)
    qb[ni] = (sec == 1) ? 0.f : qkv_b[colbase + ni * 16 + l15];

  if (sec < 2) {
    // raw (biased) q/k store, [w][h][t][32]; cosine norm deferred to attn
    u16* const base = (sec == 0) ? qn : kn;
    const int hb = (colbase % C) >> 5;
    #pragma unroll
    for (int mi = 0; mi < 2; ++mi) {
      #pragma unroll
      for (int r = 0; r < 4; ++r) {
        const int grow = m0 + wm * 32 + mi * 16 + qrt * 4 + r;
        const int w = grow >> 6, t_ = grow & 63;
        u16* dst0 = base + ((size_t)(w * 12 + hb) * 64 + t_) * 32 + l15;
        u16* dst1 = base + ((size_t)(w * 12 + hb + 1) * 64 + t_) * 32 + l15;
        dst0[0]  = f2bf(acc[mi][0][r] + qb[0]);
        dst0[16] = f2bf(acc[mi][1][r] + qb[1]);
        dst1[0]  = f2bf(acc[mi][2][r] + qb[2]);
        dst1[16] = f2bf(acc[mi][3][r] + qb[3]);
      }
    }
  } else {
    // v: per-wave 32(token) x 64(d) quadrant -> LDS transpose [d=64][t=32], 4KB/wave
    __syncthreads();                       // all waves done reading GEMM LDS
    u16* tr = &smem[0][0] + wid * 2048;    // 4KB per wave
    #pragma unroll
    for (int ni = 0; ni < 4; ++ni) {
      const int dl = ni * 16 + l15;
      #pragma unroll
      for (int mi = 0; mi < 2; ++mi) {
        const int t0 = mi * 16 + qrt * 4;        // chunk q8 = t0>>2 = mi*4+qrt
        union { u16 h[4]; uint2 u; } pk;
        #pragma unroll
        for (int r = 0; r < 4; ++r) pk.h[r] = f2bf(acc[mi][ni][r] + qb[ni]);
        const int byte = dl * 64 + (((t0 >> 2) ^ (dl & 7)) << 3);
        *(uint2*)((char*)tr + byte) = pk.u;
      }
    }
    const int w_ = (m0 + wm * 32) >> 6;
    const int tbase = (wm & 1) * 32;
    const int hbase = (colbase % C) >> 5;
    #pragma unroll
    for (int i = 0; i < 8; ++i) {
      const int d = i * 8 + (lane >> 3);
      const int ck = lane & 7;
      const int byte = d * 64 + ((ck ^ (d & 7)) << 3);
      const uint2 val = *(const uint2*)((const char*)tr + byte);
      const int head = hbase + (d >> 5), din = d & 31;
      *(uint2*)(vt + (((size_t)(w_ * 12 + head) * 32 + din) * 64 + tbase + ck * 4)) = val;
    }
  }
}

// ---------------- attention core: one wave per (window, head), SWAPPED QK^T ----------------
// acc[mi][ni] = mfma(K-rows mi, Q-rows ni) -> lane holds S[i=ni*16+l15][j=mi*16+qrt*4+r].
// Row softmax: 15 in-reg fmax + 2 shfl (was 8 shfl x 16 rows); P-strip writes packed 8B.
// Strip layout is unchanged (byte = k*2 ^ ((i&7)<<4) within row i), so PV path is identical.
__global__ __launch_bounds__(256, 4) void attn_kernel(
    const u16* __restrict__ qn, const u16* __restrict__ kn, const u16* __restrict__ vt,
    const float* __restrict__ ls, const float* __restrict__ biasf, u16* __restrict__ ao) {
  __shared__ __attribute__((aligned(16))) u16 strip_s[4][4096];   // 8KB per wave
  const int tid = threadIdx.x, lane = tid & 63, wv = tid >> 6;
  char* strip = (char*)strip_s[wv];
  const int gid = blockIdx.x * 4 + wv;        // 0..12287 = w*12+h
  const int w = gid / 12, h = gid - w * 12;
  const int win = w & 63, wy = win >> 3, wx = win & 7;
  const int l15 = lane & 15, qrt = lane >> 4;
  const f32x4 z4 = {0.f, 0.f, 0.f, 0.f};

  const u16* qh = qn + (size_t)gid * 2048;
  const u16* kh = kn + (size_t)gid * 2048;
  const u16* vh = vt + (size_t)gid * 2048;
  const float sc = __expf(fminf(ls[h], 4.605170185988091f));   // exp(min(ls, log 100))

  // load raw q/k frags, normalize per token-row (row = l15; k-chunk = qrt*8)
  s16x8 aq[4], bk[4];
  #pragma unroll
  for (int mi = 0; mi < 4; ++mi)
    aq[mi] = *(const s16x8*)(qh + (mi * 16 + l15) * 32 + qrt * 8);
  #pragma unroll
  for (int ni = 0; ni < 4; ++ni)
    bk[ni] = *(const s16x8*)(kh + (ni * 16 + l15) * 32 + qrt * 8);
  #pragma unroll
  for (int mi = 0; mi < 4; ++mi) {
    float f[8]; float ss = 0.f;
    #pragma unroll
    for (int e = 0; e < 8; ++e) { f[e] = bf2f(aq[mi][e]); ss = fmaf(f[e], f[e], ss); }
    ss += __shfl_xor(ss, 16); ss += __shfl_xor(ss, 32);
    const float rn = sc / fmaxf(sqrtf(ss), 1e-12f);
    #pragma unroll
    for (int e = 0; e < 8; ++e) aq[mi][e] = (short)f2bf(f[e] * rn);
  }
  #pragma unroll
  for (int ni = 0; ni < 4; ++ni) {
    float f[8]; float ss = 0.f;
    #pragma unroll
    for (int e = 0; e < 8; ++e) { f[e] = bf2f(bk[ni][e]); ss = fmaf(f[e], f[e], ss); }
    ss += __shfl_xor(ss, 16); ss += __shfl_xor(ss, 32);
    const float rn = 1.f / fmaxf(sqrtf(ss), 1e-12f);
    #pragma unroll
    for (int e = 0; e < 8; ++e) bk[ni][e] = (short)f2bf(f[e] * rn);
  }

  // SWAPPED: A = K-rows (mi), B = Q-rows (ni)
  f32x4 acc[4][4];   // [mi = k-block][ni = q-block]
  #pragma unroll
  for (int mi = 0; mi < 4; ++mi)
    #pragma unroll
    for (int ni = 0; ni < 4; ++ni)
      acc[mi][ni] = __builtin_amdgcn_mfma_f32_16x16x32_bf16(bk[mi], aq[ni], z4, 0, 0, 0);

  // mask classes: row i = ni*16 + l15, col j = mi*16 + qrt*4 + r
  int rcl[4];
  #pragma unroll
  for (int ni = 0; ni < 4; ++ni) {
    const int i = ni * 16 + l15;
    const int gy = wy * 8 + (i >> 3), gx = wx * 8 + (i & 7);
    rcl[ni] = ((gy < 56 ? 0 : (gy < 60 ? 1 : 2)) << 2) | (gx < 56 ? 0 : (gx < 60 ? 1 : 2));
  }
  int ccl[4][4];
  #pragma unroll
  for (int mi = 0; mi < 4; ++mi)
    #pragma unroll
    for (int r = 0; r < 4; ++r) {
      const int j = mi * 16 + qrt * 4 + r;
      const int gy = wy * 8 + (j >> 3), gx = wx * 8 + (j & 7);
      ccl[mi][r] = ((gy < 56 ? 0 : (gy < 60 ? 1 : 2)) << 2) | (gx < 56 ? 0 : (gx < 60 ? 1 : 2));
    }

  // per q-block ni: lane-local row softmax (bias table is transposed [h][j][i])
  #pragma unroll
  for (int ni = 0; ni < 4; ++ni) {
    const int i = ni * 16 + l15;
    const float* bTi = biasf + ((size_t)h << 12) + i;   // + (j<<6)
    float vv[4][4];
    float mx = -3e38f;
    #pragma unroll
    for (int mi = 0; mi < 4; ++mi)
      #pragma unroll
      for (int r = 0; r < 4; ++r) {
        const int j = mi * 16 + qrt * 4 + r;
        float val = acc[mi][ni][r] + bTi[j << 6];
        if (rcl[ni] != ccl[mi][r]) val -= 100.f;
        vv[mi][r] = val;
        mx = fmaxf(mx, val);
      }
    mx = fmaxf(mx, __shfl_xor(mx, 16));
    mx = fmaxf(mx, __shfl_xor(mx, 32));
    float sum = 0.f;
    #pragma unroll
    for (int mi = 0; mi < 4; ++mi)
      #pragma unroll
      for (int r = 0; r < 4; ++r) {
        const float pv = __expf(vv[mi][r] - mx);
        vv[mi][r] = pv; sum += pv;
      }
    sum += __shfl_xor(sum, 16);
    sum += __shfl_xor(sum, 32);
    const float inv = 1.f / sum;
    #pragma unroll
    for (int mi = 0; mi < 4; ++mi) {
      union { u16 h4[4]; uint2 u; } pk;
      #pragma unroll
      for (int r = 0; r < 4; ++r) pk.h4[r] = f2bf(vv[mi][r] * inv);
      const int byte = i * 128 + ((mi * 32 + qrt * 8) ^ ((i & 7) << 4));
      *(uint2*)(strip + byte) = pk.u;
    }
  }

  // O^T = V^T @ P^T  (unchanged: strip layout identical)
  s16x8 pa[4][2];
  #pragma unroll
  for (int ni2 = 0; ni2 < 4; ++ni2) {
    const int t = ni2 * 16 + l15;
    #pragma unroll
    for (int kk = 0; kk < 2; ++kk) {
      const int j2 = (kk * 32 + qrt * 8) * 2;
      pa[ni2][kk] = *(const s16x8*)(strip + t * 128 + (j2 ^ ((t & 7) << 4)));
    }
  }
  f32x4 o2[2][4];
  #pragma unroll
  for (int mi2 = 0; mi2 < 2; ++mi2) {
    #pragma unroll
    for (int ni2 = 0; ni2 < 4; ++ni2) o2[mi2][ni2] = z4;
    #pragma unroll
    for (int kk = 0; kk < 2; ++kk) {
      const s16x8 va = *(const s16x8*)(vh + (mi2 * 16 + l15) * 64 + kk * 32 + qrt * 8);
      #pragma unroll
      for (int ni2 = 0; ni2 < 4; ++ni2)
        o2[mi2][ni2] = __builtin_amdgcn_mfma_f32_16x16x32_bf16(va, pa[ni2][kk], o2[mi2][ni2], 0, 0, 0);
    }
  }
  // write O^T into strip as [t][d], swizzled
  #pragma unroll
  for (int mi2 = 0; mi2 < 2; ++mi2) {
    #pragma unroll
    for (int ni2 = 0; ni2 < 4; ++ni2) {
      const int t = ni2 * 16 + l15;
      #pragma unroll
      for (int rp = 0; rp < 2; ++rp) {
        const int d0 = mi2 * 16 + qrt * 4 + rp * 2;
        union { u16 h2[2]; uint32_t u; } pk;
        pk.h2[0] = f2bf(o2[mi2][ni2][rp * 2]);
        pk.h2[1] = f2bf(o2[mi2][ni2][rp * 2 + 1]);
        *(uint32_t*)(strip + t * 128 + ((d0 * 2) ^ ((t & 7) << 4))) = pk.u;
      }
    }
  }
  // coalesced store: ao[h][w*64+t][d]
  u16* aob = ao + ((size_t)h * TOK + (size_t)w * 64) * 32;
  #pragma unroll
  for (int it = 0; it < 4; ++it) {
    const int t = (lane >> 2) + it * 16, g = lane & 3;
    const uint4 val = *(const uint4*)(strip + t * 128 + ((g * 16) ^ ((t & 7) << 4)));
    *(uint4*)(aob + (size_t)t * 32 + g * 8) = val;
  }
}

// ---------------- proj GEMM (65536x384x384, BK=64, dbuf, 8 waves) + scatter ----------------
__global__ __launch_bounds__(512, 2) void proj_kernel(
    const u16* __restrict__ ao, const u16* __restrict__ pw,
    const float* __restrict__ proj_b, float* __restrict__ out) {
  __shared__ __attribute__((aligned(16))) u16 smem[4][128 * 64];   // 64KB
  const int tid = threadIdx.x, lane = tid & 63, wid = tid >> 6;
  const int l15 = lane & 15, qrt = lane >> 4;
  const int bid = blockIdx.x;                 // 1536 = 8*192
  const int swz = (bid & 7) * 192 + (bid >> 3);
  const int n_blk = swz % 3, m_blk = swz / 3;
  const int m0 = m_blk * 128, n0 = n_blk * 128;
  const int wm = wid & 3, wn = wid >> 2;

  auto stage = [&](int buf, int t) {
    #pragma unroll
    for (int it = 0; it < 2; ++it) {
      const int c = it * 512 + tid;           // 16B chunk 0..1023
      const int r = c >> 3;
      const int g = (c & 7) ^ (r & 7);
      const int p = t * 2 + (g >> 2);         // head plane of this k-granule
      async16(ao + ((size_t)p * TOK + (m0 + r)) * 32 + (g & 3) * 8, &smem[buf][c * 8]);
      async16(pw + (size_t)(n0 + r) * C + t * 64 + g * 8, &smem[2 + buf][c * 8]);
    }
  };
  auto ldfrag = [&](const u16* base, int row, int g) -> s16x8 {
    return *(const s16x8*)((const char*)base + row * 128 + ((g ^ (row & 7)) * 16));
  };

  f32x4 acc[2][4];
  #pragma unroll
  for (int i = 0; i < 2; ++i)
    #pragma unroll
    for (int j = 0; j < 4; ++j) acc[i][j] = f32x4{0.f, 0.f, 0.f, 0.f};

  stage(0, 0);
  for (int t = 0; t < 6; ++t) {
    const int buf = t & 1;
    asm volatile("s_waitcnt vmcnt(0)" ::: "memory");
    __syncthreads();
    if (t < 5) stage(buf ^ 1, t + 1);
    s16x8 af[2][2], bf[2][4];
    #pragma unroll
    for (int kk = 0; kk < 2; ++kk) {
      const int g = kk * 4 + qrt;
      #pragma unroll
      for (int mi = 0; mi < 2; ++mi)
        af[kk][mi] = ldfrag(smem[buf], wm * 32 + mi * 16 + l15, g);
      #pragma unroll
      for (int ni = 0; ni < 4; ++ni)
        bf[kk][ni] = ldfrag(smem[2 + buf], wn * 64 + ni * 16 + l15, g);
    }
    #pragma unroll
    for (int kk = 0; kk < 2; ++kk)
      #pragma unroll
      for (int mi = 0; mi < 2; ++mi)
        #pragma unroll
        for (int ni = 0; ni < 4; ++ni)
          acc[mi][ni] = __builtin_amdgcn_mfma_f32_16x16x32_bf16(af[kk][mi], bf[kk][ni], acc[mi][ni], 0, 0, 0);
  }

  // epilogue: +proj_b, window-reverse + roll(+4) scatter to f32 out
  #pragma unroll
  for (int ni = 0; ni < 4; ++ni) {
    const int n = n0 + wn * 64 + ni * 16 + l15;
    const float pb = proj_b[n];
    #pragma unroll
    for (int mi = 0; mi < 2; ++mi) {
      #pragma unroll
      for (int r = 0; r < 4; ++r) {
        const int grow = m0 + wm * 32 + mi * 16 + qrt * 4 + r;
        const int bimg = grow >> 12, win = (grow >> 6) & 63, t_ = grow & 63;
        const int y = ((win >> 3) * 8 + (t_ >> 3) + 4) & 63;
        const int xc = ((win & 7) * 8 + (t_ & 7) + 4) & 63;
        out[(((size_t)bimg * 64 + y) * 64 + xc) * C + n] = acc[mi][ni][r] + pb;
      }
    }
  }
}

extern "C" void kernel_launch(void* const* d_in, const int* in_sizes, int n_in,
                              void* d_out, int out_size, void* d_ws, size_t ws_size,
                              hipStream_t stream) {
  const float* x           = (const float*)d_in[0];
  const float* qkv_w       = (const float*)d_in[1];
  const float* qkv_b       = (const float*)d_in[2];
  const float* proj_w      = (const float*)d_in[3];
  const float* proj_b      = (const float*)d_in[4];
  const float* logit_scale = (const float*)d_in[5];
  const float* cpb_w1      = (const float*)d_in[6];
  const float* cpb_b1      = (const float*)d_in[7];
  const float* cpb_w2      = (const float*)d_in[8];
  char* ws = (char*)d_ws;
  u16* qkvwb  = (u16*)(ws + OFF_QKVW);
  u16* projwb = (u16*)(ws + OFF_PROJW);
  float* biasf = (float*)(ws + OFF_BIAS);
  u16* xg = (u16*)(ws + OFF_XG);
  u16* qn = (u16*)(ws + OFF_QN);
  u16* kn = (u16*)(ws + OFF_KN);
  u16* vt = (u16*)(ws + OFF_VT);
  float* mlp = (float*)(ws + OFF_MLP);
  u16* ao = (u16*)(ws + OFF_AO);   // aliases xg (xg dead after qkv_kernel)

  prep_kernel<<<12576, 256, 0, stream>>>(x, qkv_w, proj_w, qkvwb, projwb, xg);
  bias_mlp_kernel<<<11, 256, 0, stream>>>(cpb_w1, cpb_b1, cpb_w2, mlp);
  bias_expand_kernel<<<192, 256, 0, stream>>>(mlp, biasf);
  qkv_kernel<<<4608, 512, 0, stream>>>(xg, qkvwb, qkv_b, qn, kn, vt);
  attn_kernel<<<3072, 256, 0, stream>>>(qn, kn, vt, logit_scale, biasf, ao);
  proj_kernel<<<1536, 512, 0, stream>>>(ao, projwb, proj_b, (float*)d_out);
}

// Round 14
// 205.503 us; speedup vs baseline: 1.0870x; 1.0870x over previous
//
#include <hip/hip_runtime.h>
#include <cstdint>
#include <cstddef>

typedef unsigned short u16;
typedef __attribute__((ext_vector_type(8))) short s16x8;   // 8 bf16 (4 VGPRs) MFMA frag
typedef __attribute__((ext_vector_type(4))) float f32x4;   // MFMA accum frag

#define DEV static __device__ __forceinline__

constexpr int C = 384;
constexpr int HEADS = 12;
constexpr int NQKV = 3 * C;            // 1152
constexpr int TOK = 16 * 64 * 64;      // 65536 tokens

// workspace layout (bytes)
constexpr size_t OFF_QKVW = 0;                                        // 1152x384 bf16
constexpr size_t OFF_PROJW = OFF_QKVW + (size_t)NQKV * C * 2;         // 384x384 bf16
constexpr size_t OFF_BIAS  = OFF_PROJW + (size_t)C * C * 2;           // 12x64x64 f32
constexpr size_t OFF_XG    = OFF_BIAS + (size_t)HEADS * 64 * 64 * 4;  // 65536x384 bf16
constexpr size_t OFF_QN    = OFF_XG + (size_t)TOK * C * 2;            // [1024][12][64][32] bf16 (raw q)
constexpr size_t OFF_KN    = OFF_QN + (size_t)TOK * C * 2;            // raw k
constexpr size_t OFF_VT    = OFF_KN + (size_t)TOK * C * 2;            // [1024][12][32][64] bf16
constexpr size_t OFF_MLP   = OFF_VT + (size_t)TOK * C * 2;            // 225x12 f32
constexpr size_t OFF_AO    = OFF_XG;   // ao [12][65536][32] bf16 aliases xg (dead after qkv)

DEV u16 f2bf(float f) {
  union { float f; uint32_t u; } v; v.f = f;
  uint32_t r = v.u + 0x7FFFu + ((v.u >> 16) & 1u);   // round-to-nearest-even
  return (u16)(r >> 16);
}

DEV float bf2f(short h) {
  union { uint32_t u; float f; } v; v.u = ((uint32_t)(u16)h) << 16;
  return v.f;
}

DEV void async16(const u16* g, u16* l) {
  __builtin_amdgcn_global_load_lds((const __attribute__((address_space(1))) uint32_t*)g,
                                   (__attribute__((address_space(3))) uint32_t*)l, 16, 0, 0);
}

// ---------------- prep: bf16 weight conversion + shifted window gather of x ----------------
__global__ __launch_bounds__(256) void prep_kernel(
    const float* __restrict__ x, const float* __restrict__ qkv_w,
    const float* __restrict__ proj_w, u16* __restrict__ wq,
    u16* __restrict__ wp, u16* __restrict__ xg) {
  int idx = blockIdx.x * 256 + threadIdx.x;
  constexpr int QW = NQKV * C / 8;      // 55296 chunks of 8
  constexpr int PW = C * C / 8;         // 18432
  const float* src;
  u16* dst;
  if (idx < QW) {
    src = qkv_w + (size_t)idx * 8; dst = wq + (size_t)idx * 8;
  } else if (idx < QW + PW) {
    int i = idx - QW;
    src = proj_w + (size_t)i * 8; dst = wp + (size_t)i * 8;
  } else {
    int i = idx - QW - PW;              // 0 .. 3145727
    int r = i / 48, c8 = i % 48;        // token row, 8-elem chunk
    int b = r >> 12, w = (r >> 6) & 63, t = r & 63;
    int y  = ((w >> 3) * 8 + (t >> 3) + 4) & 63;   // roll(-4): xr[y] = x[(y+4)%64]
    int xc = ((w & 7) * 8 + (t & 7) + 4) & 63;
    src = x + (((size_t)(b * 64 + y)) * 64 + xc) * C + c8 * 8;
    dst = xg + (size_t)r * C + (size_t)c8 * 8;
  }
  float4 a = ((const float4*)src)[0];
  float4 bq = ((const float4*)src)[1];
  union { u16 h[8]; uint4 v; } o;
  o.h[0] = f2bf(a.x);  o.h[1] = f2bf(a.y);  o.h[2] = f2bf(a.z);  o.h[3] = f2bf(a.w);
  o.h[4] = f2bf(bq.x); o.h[5] = f2bf(bq.y); o.h[6] = f2bf(bq.z); o.h[7] = f2bf(bq.w);
  *(uint4*)dst = o.v;
}

// ---------------- cpb MLP (parallel over 225 points x 12 heads) ----------------
__global__ __launch_bounds__(256) void bias_mlp_kernel(
    const float* __restrict__ w1, const float* __restrict__ b1,
    const float* __restrict__ w2, float* __restrict__ mlp_out) {
  const int gid = blockIdx.x * 256 + threadIdx.x;
  if (gid >= 225 * 12) return;
  const int pt = gid / 12, q = gid % 12;
  const int a = pt / 15, b = pt % 15;
  const float dy = (float)(a - 7) * (8.f / 7.f);
  const float dx = (float)(b - 7) * (8.f / 7.f);
  const float t0 = copysignf(log2f(fabsf(dy) + 1.f) * (1.f / 3.f), dy);
  const float t1 = copysignf(log2f(fabsf(dx) + 1.f) * (1.f / 3.f), dx);
  float acc = 0.f;
  for (int j = 0; j < 512; ++j) {
    const float hh = fmaxf(w1[2 * j] * t0 + w1[2 * j + 1] * t1 + b1[j], 0.f);
    acc += hh * w2[q * 512 + j];
  }
  mlp_out[gid] = acc;
}

// ---------------- expand to 16*sigmoid bias (12,64,64) f32 ----------------
__global__ __launch_bounds__(256) void bias_expand_kernel(
    const float* __restrict__ mlp_out, float* __restrict__ biasf) {
  const int o = blockIdx.x * 256 + threadIdx.x;   // < 49152
  const int j = o & 63, i = (o >> 6) & 63, h = o >> 12;
  const int e = ((i >> 3) - (j >> 3) + 7) * 15 + ((i & 7) - (j & 7) + 7);
  const float v = mlp_out[e * 12 + h];
  biasf[o] = 16.f / (1.f + __expf(-v));
}

// ---------------- QKV GEMM (128x128, BK=64, dbuf, 8 waves) + epilogue ----------------
// LDS tile per matrix per buf: 128 rows x 64 k, row r = 128B at byte r*128;
// granule g (16B) at ((g ^ (r&7))*16). Staged linearly by chunk c with the
// inverse swizzle applied on the SOURCE k-granule (rule #21).
__global__ __launch_bounds__(512, 2) void qkv_kernel(
    const u16* __restrict__ xg, const u16* __restrict__ wq,
    const float* __restrict__ qkv_b,
    u16* __restrict__ qn, u16* __restrict__ kn, u16* __restrict__ vt) {
  __shared__ __attribute__((aligned(16))) u16 smem[4][128 * 64];   // A0 A1 B0 B1 = 64KB
  const int tid = threadIdx.x, lane = tid & 63, wid = tid >> 6;
  const int l15 = lane & 15, qrt = lane >> 4;
  const int bid = blockIdx.x;
  const int swz = (bid & 7) * 576 + (bid >> 3);
  const int n_blk = swz % 9, m_blk = swz / 9;
  const int m0 = m_blk * 128, n0 = n_blk * 128;
  const int wm = wid & 3, wn = wid >> 2;       // wave tile: 32 rows x 64 cols

  auto stage = [&](int buf, int t) {
    const int k0 = t * 64;
    #pragma unroll
    for (int it = 0; it < 2; ++it) {
      const int c = it * 512 + tid;           // 16B chunk 0..1023
      const int r = c >> 3;
      const int g = (c & 7) ^ (r & 7);
      async16(xg + (size_t)(m0 + r) * C + k0 + g * 8, &smem[buf][c * 8]);
      async16(wq + (size_t)(n0 + r) * C + k0 + g * 8, &smem[2 + buf][c * 8]);
    }
  };
  auto ldfrag = [&](const u16* base, int row, int g) -> s16x8 {
    return *(const s16x8*)((const char*)base + row * 128 + ((g ^ (row & 7)) * 16));
  };

  f32x4 acc[2][4];
  #pragma unroll
  for (int i = 0; i < 2; ++i)
    #pragma unroll
    for (int j = 0; j < 4; ++j) acc[i][j] = f32x4{0.f, 0.f, 0.f, 0.f};

  stage(0, 0);
  for (int t = 0; t < 6; ++t) {
    const int buf = t & 1;
    asm volatile("s_waitcnt vmcnt(0)" ::: "memory");
    __syncthreads();
    if (t < 5) stage(buf ^ 1, t + 1);
    s16x8 af[2][2], bf[2][4];
    #pragma unroll
    for (int kk = 0; kk < 2; ++kk) {
      const int g = kk * 4 + qrt;
      #pragma unroll
      for (int mi = 0; mi < 2; ++mi)
        af[kk][mi] = ldfrag(smem[buf], wm * 32 + mi * 16 + l15, g);
      #pragma unroll
      for (int ni = 0; ni < 4; ++ni)
        bf[kk][ni] = ldfrag(smem[2 + buf], wn * 64 + ni * 16 + l15, g);
    }
    #pragma unroll
    for (int kk = 0; kk < 2; ++kk)
      #pragma unroll
      for (int mi = 0; mi < 2; ++mi)
        #pragma unroll
        for (int ni = 0; ni < 4; ++ni)
          acc[mi][ni] = __builtin_amdgcn_mfma_f32_16x16x32_bf16(af[kk][mi], bf[kk][ni], acc[mi][ni], 0, 0, 0);
  }

  const int sec = n0 / C;                 // 0=q 1=k 2=v
  const int colbase = n0 + wn * 64;
  float qb[4];
  #pragma unroll
  for (int ni = 0; ni < 4; ++ni)
    qb[ni] = (sec == 1) ? 0.f : qkv_b[colbase + ni * 16 + l15];

  if (sec < 2) {
    // raw (biased) q/k store, [w][h][t][32]; cosine norm deferred to attn
    u16* const base = (sec == 0) ? qn : kn;
    const int hb = (colbase % C) >> 5;
    #pragma unroll
    for (int mi = 0; mi < 2; ++mi) {
      #pragma unroll
      for (int r = 0; r < 4; ++r) {
        const int grow = m0 + wm * 32 + mi * 16 + qrt * 4 + r;
        const int w = grow >> 6, t_ = grow & 63;
        u16* dst0 = base + ((size_t)(w * 12 + hb) * 64 + t_) * 32 + l15;
        u16* dst1 = base + ((size_t)(w * 12 + hb + 1) * 64 + t_) * 32 + l15;
        dst0[0]  = f2bf(acc[mi][0][r] + qb[0]);
        dst0[16] = f2bf(acc[mi][1][r] + qb[1]);
        dst1[0]  = f2bf(acc[mi][2][r] + qb[2]);
        dst1[16] = f2bf(acc[mi][3][r] + qb[3]);
      }
    }
  } else {
    // v: per-wave 32(token) x 64(d) quadrant -> LDS transpose [d=64][t=32], 4KB/wave
    __syncthreads();                       // all waves done reading GEMM LDS
    u16* tr = &smem[0][0] + wid * 2048;    // 4KB per wave
    #pragma unroll
    for (int ni = 0; ni < 4; ++ni) {
      const int dl = ni * 16 + l15;
      #pragma unroll
      for (int mi = 0; mi < 2; ++mi) {
        const int t0 = mi * 16 + qrt * 4;        // chunk q8 = t0>>2 = mi*4+qrt
        union { u16 h[4]; uint2 u; } pk;
        #pragma unroll
        for (int r = 0; r < 4; ++r) pk.h[r] = f2bf(acc[mi][ni][r] + qb[ni]);
        const int byte = dl * 64 + (((t0 >> 2) ^ (dl & 7)) << 3);
        *(uint2*)((char*)tr + byte) = pk.u;
      }
    }
    const int w_ = (m0 + wm * 32) >> 6;
    const int tbase = (wm & 1) * 32;
    const int hbase = (colbase % C) >> 5;
    #pragma unroll
    for (int i = 0; i < 8; ++i) {
      const int d = i * 8 + (lane >> 3);
      const int ck = lane & 7;
      const int byte = d * 64 + ((ck ^ (d & 7)) << 3);
      const uint2 val = *(const uint2*)((const char*)tr + byte);
      const int head = hbase + (d >> 5), din = d & 31;
      *(uint2*)(vt + (((size_t)(w_ * 12 + head) * 32 + din) * 64 + tbase + ck * 4)) = val;
    }
  }
}

// ---------------- attention core: one wave per (window, head), in-reg cosine norm ----------------
__global__ __launch_bounds__(256, 4) void attn_kernel(
    const u16* __restrict__ qn, const u16* __restrict__ kn, const u16* __restrict__ vt,
    const float* __restrict__ ls, const float* __restrict__ biasf, u16* __restrict__ ao) {
  __shared__ __attribute__((aligned(16))) u16 strip_s[4][4096];   // 8KB per wave
  const int tid = threadIdx.x, lane = tid & 63, wv = tid >> 6;
  char* strip = (char*)strip_s[wv];
  const int gid = blockIdx.x * 4 + wv;        // 0..12287 = w*12+h
  const int w = gid / 12, h = gid - w * 12;
  const int win = w & 63, wy = win >> 3, wx = win & 7;
  const int l15 = lane & 15, qrt = lane >> 4;
  const f32x4 z4 = {0.f, 0.f, 0.f, 0.f};

  const u16* qh = qn + (size_t)gid * 2048;
  const u16* kh = kn + (size_t)gid * 2048;
  const u16* vh = vt + (size_t)gid * 2048;
  const float sc = __expf(fminf(ls[h], 4.605170185988091f));   // exp(min(ls, log 100))

  // load raw q/k frags, normalize per token-row (row = l15; k-chunk = qrt*8)
  s16x8 aq[4], bk[4];
  #pragma unroll
  for (int mi = 0; mi < 4; ++mi)
    aq[mi] = *(const s16x8*)(qh + (mi * 16 + l15) * 32 + qrt * 8);
  #pragma unroll
  for (int ni = 0; ni < 4; ++ni)
    bk[ni] = *(const s16x8*)(kh + (ni * 16 + l15) * 32 + qrt * 8);
  #pragma unroll
  for (int mi = 0; mi < 4; ++mi) {
    float f[8]; float ss = 0.f;
    #pragma unroll
    for (int e = 0; e < 8; ++e) { f[e] = bf2f(aq[mi][e]); ss = fmaf(f[e], f[e], ss); }
    ss += __shfl_xor(ss, 16); ss += __shfl_xor(ss, 32);
    const float rn = sc / fmaxf(sqrtf(ss), 1e-12f);
    #pragma unroll
    for (int e = 0; e < 8; ++e) aq[mi][e] = (short)f2bf(f[e] * rn);
  }
  #pragma unroll
  for (int ni = 0; ni < 4; ++ni) {
    float f[8]; float ss = 0.f;
    #pragma unroll
    for (int e = 0; e < 8; ++e) { f[e] = bf2f(bk[ni][e]); ss = fmaf(f[e], f[e], ss); }
    ss += __shfl_xor(ss, 16); ss += __shfl_xor(ss, 32);
    const float rn = 1.f / fmaxf(sqrtf(ss), 1e-12f);
    #pragma unroll
    for (int e = 0; e < 8; ++e) bk[ni][e] = (short)f2bf(f[e] * rn);
  }

  f32x4 acc[4][4];
  #pragma unroll
  for (int mi = 0; mi < 4; ++mi)
    #pragma unroll
    for (int ni = 0; ni < 4; ++ni)
      acc[mi][ni] = __builtin_amdgcn_mfma_f32_16x16x32_bf16(aq[mi], bk[ni], z4, 0, 0, 0);

  // column (j) mask classes
  int ccls[4];
  #pragma unroll
  for (int ni = 0; ni < 4; ++ni) {
    const int j = ni * 16 + l15;
    const int gy = wy * 8 + (j >> 3), gx = wx * 8 + (j & 7);
    ccls[ni] = ((gy < 56 ? 0 : (gy < 60 ? 1 : 2)) << 2) | (gx < 56 ? 0 : (gx < 60 ? 1 : 2));
  }

  // softmax per row i
  #pragma unroll
  for (int mi = 0; mi < 4; ++mi) {
    #pragma unroll
    for (int r = 0; r < 4; ++r) {
      const int i = mi * 16 + qrt * 4 + r;
      const int gy = wy * 8 + (i >> 3), gx = wx * 8 + (i & 7);
      const int rcl = ((gy < 56 ? 0 : (gy < 60 ? 1 : 2)) << 2) | (gx < 56 ? 0 : (gx < 60 ? 1 : 2));
      const float* brow = biasf + ((h << 6) + i) * 64 + l15;
      float mx = -3e38f;
      #pragma unroll
      for (int ni = 0; ni < 4; ++ni) {
        float val = acc[mi][ni][r] + brow[ni * 16];
        if (rcl != ccls[ni]) val -= 100.f;
        acc[mi][ni][r] = val;
        mx = fmaxf(mx, val);
      }
      mx = fmaxf(mx, __shfl_xor(mx, 1));
      mx = fmaxf(mx, __shfl_xor(mx, 2));
      mx = fmaxf(mx, __shfl_xor(mx, 4));
      mx = fmaxf(mx, __shfl_xor(mx, 8));
      float sum = 0.f;
      #pragma unroll
      for (int ni = 0; ni < 4; ++ni) {
        const float pv = __expf(acc[mi][ni][r] - mx);
        acc[mi][ni][r] = pv; sum += pv;
      }
      sum += __shfl_xor(sum, 1); sum += __shfl_xor(sum, 2);
      sum += __shfl_xor(sum, 4); sum += __shfl_xor(sum, 8);
      const float inv = 1.f / sum;
      #pragma unroll
      for (int ni = 0; ni < 4; ++ni) {
        const int j2 = (ni * 16 + l15) * 2;
        *(u16*)(strip + i * 128 + (j2 ^ ((i & 7) << 4))) = f2bf(acc[mi][ni][r] * inv);
      }
    }
  }

  // O^T = V^T @ P^T
  s16x8 pa[4][2];
  #pragma unroll
  for (int ni2 = 0; ni2 < 4; ++ni2) {
    const int t = ni2 * 16 + l15;
    #pragma unroll
    for (int kk = 0; kk < 2; ++kk) {
      const int j2 = (kk * 32 + qrt * 8) * 2;
      pa[ni2][kk] = *(const s16x8*)(strip + t * 128 + (j2 ^ ((t & 7) << 4)));
    }
  }
  f32x4 o2[2][4];
  #pragma unroll
  for (int mi2 = 0; mi2 < 2; ++mi2) {
    #pragma unroll
    for (int ni2 = 0; ni2 < 4; ++ni2) o2[mi2][ni2] = z4;
    #pragma unroll
    for (int kk = 0; kk < 2; ++kk) {
      const s16x8 va = *(const s16x8*)(vh + (mi2 * 16 + l15) * 64 + kk * 32 + qrt * 8);
      #pragma unroll
      for (int ni2 = 0; ni2 < 4; ++ni2)
        o2[mi2][ni2] = __builtin_amdgcn_mfma_f32_16x16x32_bf16(va, pa[ni2][kk], o2[mi2][ni2], 0, 0, 0);
    }
  }
  // write O^T into strip as [t][d], swizzled
  #pragma unroll
  for (int mi2 = 0; mi2 < 2; ++mi2) {
    #pragma unroll
    for (int ni2 = 0; ni2 < 4; ++ni2) {
      const int t = ni2 * 16 + l15;
      #pragma unroll
      for (int rp = 0; rp < 2; ++rp) {
        const int d0 = mi2 * 16 + qrt * 4 + rp * 2;
        union { u16 h2[2]; uint32_t u; } pk;
        pk.h2[0] = f2bf(o2[mi2][ni2][rp * 2]);
        pk.h2[1] = f2bf(o2[mi2][ni2][rp * 2 + 1]);
        *(uint32_t*)(strip + t * 128 + ((d0 * 2) ^ ((t & 7) << 4))) = pk.u;
      }
    }
  }
  // coalesced store: ao[h][w*64+t][d]
  u16* aob = ao + ((size_t)h * TOK + (size_t)w * 64) * 32;
  #pragma unroll
  for (int it = 0; it < 4; ++it) {
    const int t = (lane >> 2) + it * 16, g = lane & 3;
    const uint4 val = *(const uint4*)(strip + t * 128 + ((g * 16) ^ ((t & 7) << 4)));
    *(uint4*)(aob + (size_t)t * 32 + g * 8) = val;
  }
}

// ---------------- proj GEMM (65536x384x384, BK=64, dbuf, 8 waves) + scatter ----------------
__global__ __launch_bounds__(512, 2) void proj_kernel(
    const u16* __restrict__ ao, const u16* __restrict__ pw,
    const float* __restrict__ proj_b, float* __restrict__ out) {
  __shared__ __attribute__((aligned(16))) u16 smem[4][128 * 64];   // 64KB
  const int tid = threadIdx.x, lane = tid & 63, wid = tid >> 6;
  const int l15 = lane & 15, qrt = lane >> 4;
  const int bid = blockIdx.x;                 // 1536 = 8*192
  const int swz = (bid & 7) * 192 + (bid >> 3);
  const int n_blk = swz % 3, m_blk = swz / 3;
  const int m0 = m_blk * 128, n0 = n_blk * 128;
  const int wm = wid & 3, wn = wid >> 2;

  auto stage = [&](int buf, int t) {
    #pragma unroll
    for (int it = 0; it < 2; ++it) {
      const int c = it * 512 + tid;           // 16B chunk 0..1023
      const int r = c >> 3;
      const int g = (c & 7) ^ (r & 7);
      const int p = t * 2 + (g >> 2);         // head plane of this k-granule
      async16(ao + ((size_t)p * TOK + (m0 + r)) * 32 + (g & 3) * 8, &smem[buf][c * 8]);
      async16(pw + (size_t)(n0 + r) * C + t * 64 + g * 8, &smem[2 + buf][c * 8]);
    }
  };
  auto ldfrag = [&](const u16* base, int row, int g) -> s16x8 {
    return *(const s16x8*)((const char*)base + row * 128 + ((g ^ (row & 7)) * 16));
  };

  f32x4 acc[2][4];
  #pragma unroll
  for (int i = 0; i < 2; ++i)
    #pragma unroll
    for (int j = 0; j < 4; ++j) acc[i][j] = f32x4{0.f, 0.f, 0.f, 0.f};

  stage(0, 0);
  for (int t = 0; t < 6; ++t) {
    const int buf = t & 1;
    asm volatile("s_waitcnt vmcnt(0)" ::: "memory");
    __syncthreads();
    if (t < 5) stage(buf ^ 1, t + 1);
    s16x8 af[2][2], bf[2][4];
    #pragma unroll
    for (int kk = 0; kk < 2; ++kk) {
      const int g = kk * 4 + qrt;
      #pragma unroll
      for (int mi = 0; mi < 2; ++mi)
        af[kk][mi] = ldfrag(smem[buf], wm * 32 + mi * 16 + l15, g);
      #pragma unroll
      for (int ni = 0; ni < 4; ++ni)
        bf[kk][ni] = ldfrag(smem[2 + buf], wn * 64 + ni * 16 + l15, g);
    }
    #pragma unroll
    for (int kk = 0; kk < 2; ++kk)
      #pragma unroll
      for (int mi = 0; mi < 2; ++mi)
        #pragma unroll
        for (int ni = 0; ni < 4; ++ni)
          acc[mi][ni] = __builtin_amdgcn_mfma_f32_16x16x32_bf16(af[kk][mi], bf[kk][ni], acc[mi][ni], 0, 0, 0);
  }

  // epilogue: +proj_b, window-reverse + roll(+4) scatter to f32 out
  #pragma unroll
  for (int ni = 0; ni < 4; ++ni) {
    const int n = n0 + wn * 64 + ni * 16 + l15;
    const float pb = proj_b[n];
    #pragma unroll
    for (int mi = 0; mi < 2; ++mi) {
      #pragma unroll
      for (int r = 0; r < 4; ++r) {
        const int grow = m0 + wm * 32 + mi * 16 + qrt * 4 + r;
        const int bimg = grow >> 12, win = (grow >> 6) & 63, t_ = grow & 63;
        const int y = ((win >> 3) * 8 + (t_ >> 3) + 4) & 63;
        const int xc = ((win & 7) * 8 + (t_ & 7) + 4) & 63;
        out[(((size_t)bimg * 64 + y) * 64 + xc) * C + n] = acc[mi][ni][r] + pb;
      }
    }
  }
}

extern "C" void kernel_launch(void* const* d_in, const int* in_sizes, int n_in,
                              void* d_out, int out_size, void* d_ws, size_t ws_size,
                              hipStream_t stream) {
  const float* x           = (const float*)d_in[0];
  const float* qkv_w       = (const float*)d_in[1];
  const float* qkv_b       = (const float*)d_in[2];
  const float* proj_w      = (const float*)d_in[3];
  const float* proj_b      = (const float*)d_in[4];
  const float* logit_scale = (const float*)d_in[5];
  const float* cpb_w1      = (const float*)d_in[6];
  const float* cpb_b1      = (const float*)d_in[7];
  const float* cpb_w2      = (const float*)d_in[8];
  char* ws = (char*)d_ws;
  u16* qkvwb  = (u16*)(ws + OFF_QKVW);
  u16* projwb = (u16*)(ws + OFF_PROJW);
  float* biasf = (float*)(ws + OFF_BIAS);
  u16* xg = (u16*)(ws + OFF_XG);
  u16* qn = (u16*)(ws + OFF_QN);
  u16* kn = (u16*)(ws + OFF_KN);
  u16* vt = (u16*)(ws + OFF_VT);
  float* mlp = (float*)(ws + OFF_MLP);
  u16* ao = (u16*)(ws + OFF_AO);   // aliases xg (xg dead after qkv_kernel)

  prep_kernel<<<12576, 256, 0, stream>>>(x, qkv_w, proj_w, qkvwb, projwb, xg);
  bias_mlp_kernel<<<11, 256, 0, stream>>>(cpb_w1, cpb_b1, cpb_w2, mlp);
  bias_expand_kernel<<<192, 256, 0, stream>>>(mlp, biasf);
  qkv_kernel<<<4608, 512, 0, stream>>>(xg, qkvwb, qkv_b, qn, kn, vt);
  attn_kernel<<<3072, 256, 0, stream>>>(qn, kn, vt, logit_scale, biasf, ao);
  proj_kernel<<<1536, 512, 0, stream>>>(ao, projwb, proj_b, (float*)d_out);
}